// Round 12
// baseline (2613.463 us; speedup 1.0000x reference)
//
#include <hip/hip_runtime.h>
#include <hip/hip_bf16.h>
#include <stdint.h>

// SymmetricHyperRBM on MI355X. K=10 Gibbs chain + free-energy gap.
// fp8 e4m3; FiLM biases folded into GEMM K-dim; XOR-swizzled LDS; XCD swizzle.
// u-chain decoupled via per-step scalars (hz,hw,sbm from EPI0; hcm from EPI1),
// resolved in k_uchain. Bias-dots fused into the 1024-block grid as a 16-row
// mini B-fragment. R11 BUG FIX: accB is wn-independent, so only the wn==0
// wave of each wm-pair may emit the bias-dot (R11 double-counted -> 2x sbm).

#define NB 16384
#define KSTEPS 10
#define LDA 1152           // bytes/row: 1024 state + 64 X + 1 const + 63 pad
#define SLS 136            // epilogue slab row stride in bytes (128 + 8 pad)
#define USALT 4000u
#define ONE8 ((unsigned char)0x38)  // fp8 e4m3 1.0

typedef __attribute__((ext_vector_type(4))) float f32x4;
typedef __attribute__((ext_vector_type(4))) unsigned int u32x4;

__device__ __forceinline__ unsigned hash32(unsigned idx, unsigned salt) {
  unsigned x = idx + salt * 0x9E3779B9u;
  x = (x ^ (x >> 16)) * 0x7feb352du;
  x = (x ^ (x >> 15)) * 0x846ca68bu;
  return x ^ (x >> 16);
}
__device__ __forceinline__ float rng_u01(unsigned salt, unsigned idx) {
  return (float)(hash32(idx, salt) >> 8) * (1.0f / 16777216.0f);
}
__device__ __forceinline__ float sigm(float z) { return 1.0f / (1.0f + __expf(-z)); }
__device__ __forceinline__ float softplus_(float z) {
  return z > 0.f ? z + log1pf(__expf(-z)) : log1pf(__expf(z));
}
__device__ __forceinline__ float lse2(float a, float b) {
  float m = fmaxf(a, b);
  return m + log1pf(__expf(fminf(a, b) - m));
}
__device__ __forceinline__ float bf2f(unsigned short s) {
  unsigned u = ((unsigned)s) << 16;
  return *reinterpret_cast<float*>(&u);
}
__device__ __forceinline__ unsigned short f2bf(float f) {
  __hip_bfloat16 h = __float2bfloat16(f);
  return *reinterpret_cast<unsigned short*>(&h);
}
// float -> fp8 e4m3fn (OCP), RNE, saturating. Setup-path only.
__device__ unsigned char f2e4m3(float f) {
  unsigned u = __float_as_uint(f);
  unsigned char s = (unsigned char)((u >> 24) & 0x80);
  float af = fabsf(f);
  if (af >= 448.f) return s | 0x7E;
  float sub = rintf(af * 512.f);
  if (sub < 1.f) return s;                 // underflow -> 0
  if (af < 0.015625f) {                    // subnormal, step 2^-9
    int m = (int)sub;
    if (m > 7) return s | 0x08;
    return s | (unsigned char)m;
  }
  int ex; frexpf(af, &ex);
  int E = ex - 1;                          // af in [2^E, 2^(E+1))
  float q = rintf(ldexpf(af, 3 - E));      // in [8,16]
  int qi = (int)q;
  if (qi >= 16) { qi = 8; E += 1; if (E > 8) return s | 0x7E; }
  return s | (unsigned char)(((E + 7) << 3) | (qi - 8));
}
__device__ __forceinline__ void gl2lds16(const void* g, void* l) {
  __builtin_amdgcn_global_load_lds(
      (const __attribute__((address_space(1))) unsigned int*)g,
      (__attribute__((address_space(3))) unsigned int*)l, 16, 0, 0);
}

// ---------------------------------------------------------------------------
// C = A[16384 x Kdim] * Bt[. x Kdim]^T, fp8 MFMA 16x16x32, 128x128, BK=128.
// Grid 1024: xcd=L&7, li=L>>3; m-tile = xcd*16 + (li&15); n-tile jt = li>>4.
// Every block also processes a 16-row bias mini-tile (B rows 1024+jt*16..+16)
// into accB; the wn==0 wave of each wm-half dots accB with X -> r2.
// EPI 0: h=bern(sigm(z1)) -> sh; reduces hz=sum h*z1 (r0), hw=sum h*wcs (r1).
// EPI 1: s=bern(sigm(z2)) -> sh (pure sampler).
// EPI 2: softplus rows (cmod NT; branch swap by ub) -> r0,r1.
// ---------------------------------------------------------------------------
template <int EPI>
__global__ __launch_bounds__(256, 4) void gemm_bt(
    const unsigned char* __restrict__ A, const unsigned char* __restrict__ Bt,
    unsigned char* sh, const unsigned short* __restrict__ mod,
    const float* __restrict__ wcs, const float* __restrict__ Xf,
    const unsigned char* __restrict__ ub,
    float* __restrict__ r0, float* __restrict__ r1, float* __restrict__ r2,
    unsigned salt, int Kdim) {
  // staging: As [0,16K) Bs [16K,32K) Bbias [32K,34K); slab aliases front
  __shared__ __align__(16) char smem[34816];
  unsigned char* newsl = (unsigned char*)smem;

  const int t = threadIdx.x;
  const int L = blockIdx.x;
  const int xcd = L & 7, li = L >> 3;
  const int m0 = (xcd * 16 + (li & 15)) * 128;
  const int jt = li >> 4;              // n-tile 0..7
  const int n0 = jt * 128;
  const int lane = t & 63, wave = t >> 6;
  const int wm = (wave >> 1) * 64, wn = (wave & 1) * 64;
  const int lr = lane & 15, quad = lane >> 4;
  // staging: lane -> row i>>3, phys chunk i&7, gathers LOGICAL chunk (i&7)^(i>>3)
  const int srow = lane >> 3;
  const int sq16 = (((lane & 7) ^ srow) << 4);
  // fragment read offsets: logical chunk s*2+(quad>>1), row-xor lr&7
  const int ql8 = (quad & 1) * 8, qh = quad >> 1, lx = lr & 7;
  int koff[4];
#pragma unroll
  for (int s = 0; s < 4; ++s) koff[s] = (((s * 2 + qh) ^ lx) << 4) + ql8;

  // hoisted staging pointers (advance by 128 B per K-iter)
  const unsigned char* gA[4];
  const unsigned char* gB[4];
#pragma unroll
  for (int c = 0; c < 4; ++c) {
    const int row = (wave * 4 + c) * 8 + srow;
    gA[c] = A + (size_t)(m0 + row) * LDA + sq16;
    gB[c] = Bt + (size_t)(n0 + row) * LDA + sq16;
  }
  const unsigned char* gBb =
      Bt + (size_t)(1024 + jt * 16 + (wave & 1) * 8 + srow) * LDA + sq16;

  f32x4 acc[4][4] = {};
  f32x4 accB[4] = {};  // bias mini-tile, col = jt*16 + lr (wn-INDEPENDENT)

  for (int k0 = 0; k0 < Kdim; k0 += 128) {
#pragma unroll
    for (int c = 0; c < 4; ++c) {
      gl2lds16(gA[c], smem + (wave * 4 + c) * 1024);
      gA[c] += 128;
      gl2lds16(gB[c], smem + 16384 + (wave * 4 + c) * 1024);
      gB[c] += 128;
    }
    if (wave < 2) { gl2lds16(gBb, smem + 32768 + wave * 1024); gBb += 128; }
    __syncthreads();
#pragma unroll
    for (int s = 0; s < 4; ++s) {  // four K=32 slices of the 128-B row
      long af[4], bfr[4], bb;
#pragma unroll
      for (int i = 0; i < 4; i++)
        af[i] = *(const long*)(smem + (wm + i * 16 + lr) * 128 + koff[s]);
#pragma unroll
      for (int j = 0; j < 4; j++)
        bfr[j] = *(const long*)(smem + 16384 + (wn + j * 16 + lr) * 128 + koff[s]);
      bb = *(const long*)(smem + 32768 + lr * 128 + koff[s]);
#pragma unroll
      for (int i = 0; i < 4; i++) {
#pragma unroll
        for (int j = 0; j < 4; j++)
          acc[i][j] = __builtin_amdgcn_mfma_f32_16x16x32_fp8_fp8(af[i], bfr[j], acc[i][j], 0, 0, 0);
        accB[i] = __builtin_amdgcn_mfma_f32_16x16x32_fp8_fp8(af[i], bb, accB[i], 0, 0, 0);
      }
    }
    __syncthreads();
  }

  // C/D layout (m89, dtype-independent): col = lane&15, row = quad*4 + reg
  // ---- bias-dot epilogue: ONLY the wn==0 wave of each wm-half emits
  // (accB is identical across the wn-pair -> emitting from both = 2x bug).
  if (jt <= 4 && wn == 0) {
    const int cg = jt * 16 + lr;
#pragma unroll
    for (int i = 0; i < 4; i++)
#pragma unroll
      for (int rg = 0; rg < 4; rg++) {
        const int r = m0 + wm + i * 16 + quad * 4 + rg;
        float pb;
        if (jt < 4) pb = accB[i][rg] * Xf[(size_t)r * 64 + cg];
        else pb = (lr == 0) ? accB[i][rg] : 0.f;  // col 1088 = cst-dot
#pragma unroll
        for (int msk = 1; msk < 16; msk <<= 1) pb += __shfl_xor(pb, msk, 64);
        if (lr == 0) atomicAdd(&r2[r], pb);
      }
  }

  if constexpr (EPI == 2) {
#pragma unroll
    for (int i = 0; i < 4; i++)
#pragma unroll
      for (int rg = 0; rg < 4; rg++) {
        const int r = m0 + wm + i * 16 + quad * 4 + rg;
        const bool uu = (ub == nullptr) ? true : (ub[r] != 0);
        float sn = 0.f, sf = 0.f;
#pragma unroll
        for (int j = 0; j < 4; j++) {
          const int n = n0 + wn + j * 16 + lr;
          const float vw = acc[i][j][rg];
          const float cm = bf2f(__builtin_nontemporal_load(mod + (size_t)r * 1024 + n));
          const float s1 = softplus_(vw + cm);
          const float s2 = softplus_(wcs[n] - vw + cm);
          sn += uu ? s1 : s2;
          sf += uu ? s2 : s1;
        }
#pragma unroll
        for (int msk = 1; msk < 16; msk <<= 1) {
          sn += __shfl_xor(sn, msk, 64);
          sf += __shfl_xor(sf, msk, 64);
        }
        if (lr == 0) { atomicAdd(&r0[r], sn); atomicAdd(&r1[r], sf); }
      }
    return;
  }

  // EPI 0/1: sample into slab; EPI0 also reduces hz (sum h*z1), hw (sum h*wcs)
  float wv[4];
  if constexpr (EPI == 0) {
#pragma unroll
    for (int j = 0; j < 4; j++) wv[j] = wcs[n0 + wn + j * 16 + lr];
  }
#pragma unroll
  for (int i = 0; i < 4; ++i)
#pragma unroll
    for (int rg = 0; rg < 4; ++rg) {
      const int rowl = wm + i * 16 + quad * 4 + rg;  // 0..127 in tile
      const int r = m0 + rowl;
      float hzp = 0.f, hwp = 0.f;
#pragma unroll
      for (int jp = 0; jp < 2; ++jp) {
        const unsigned x = hash32((unsigned)(r << 10) + (unsigned)(n0 + wn + jp * 16 + lr), salt);
        const float f0 = (float)(x & 0xFFFFu), f1 = (float)(x >> 16);
        const float z0 = acc[i][jp][rg], z1v = acc[i][jp + 2][rg];
        const bool b0 = (f0 * __expf(-z0) < 65536.f - f0);
        const bool b1 = (f1 * __expf(-z1v) < 65536.f - f1);
        newsl[rowl * SLS + wn + jp * 16 + lr] = b0 ? ONE8 : (unsigned char)0;
        newsl[rowl * SLS + wn + (jp + 2) * 16 + lr] = b1 ? ONE8 : (unsigned char)0;
        if constexpr (EPI == 0) {
          if (b0) { hzp += z0; hwp += wv[jp]; }
          if (b1) { hzp += z1v; hwp += wv[jp + 2]; }
        }
      }
      if constexpr (EPI == 0) {
#pragma unroll
        for (int msk = 1; msk < 16; msk <<= 1) {
          hzp += __shfl_xor(hzp, msk, 64);
          hwp += __shfl_xor(hwp, msk, 64);
        }
        if (lr == 0) { atomicAdd(&r0[r], hzp); atomicAdd(&r1[r], hwp); }
      }
    }
  __syncthreads();
#pragma unroll
  for (int p = 0; p < 4; ++p) {  // 128 rows x 128 B, fully coalesced
    const int c = p * 256 + t, rowl = c >> 3, chk = c & 7;
    const u32x4 vv = *(const u32x4*)(newsl + rowl * SLS + chk * 16);
    *(u32x4*)(sh + (size_t)(m0 + rowl) * LDA + n0 + chk * 16) = vv;
  }
}

// ------------------------- setup / small kernels ---------------------------
__global__ __launch_bounds__(256) void k_x(const float* __restrict__ cond,
                                           const float* __restrict__ fc1w,
                                           const float* __restrict__ fc1b, float* __restrict__ X) {
  int idx = blockIdx.x * 256 + threadIdx.x;
  int r = idx >> 6, k = idx & 63;
  X[idx] = tanhf(cond[r] * fc1w[k] + fc1b[k]);
}

__global__ __launch_bounds__(256) void k_g(const float* __restrict__ fc2w,
                                           const float* __restrict__ fc2b,
                                           const float* __restrict__ b, const float* __restrict__ c,
                                           float* __restrict__ Gb, float* __restrict__ Gc,
                                           float* __restrict__ cstb, float* __restrict__ cstc) {
  int idx = blockIdx.x * 256 + threadIdx.x;
  int j = idx >> 6, k = idx & 63;
  Gb[idx] = fc2w[(size_t)j * 64 + k] * b[j] + fc2w[(size_t)(1024 + j) * 64 + k];
  Gc[idx] = fc2w[(size_t)(2048 + j) * 64 + k] * c[j] + fc2w[(size_t)(3072 + j) * 64 + k];
  if (k == 0) {
    cstb[j] = b[j] + fc2b[j] * b[j] + fc2b[1024 + j];
    cstc[j] = c[j] + fc2b[2048 + j] * c[j] + fc2b[3072 + j];
  }
}

// Wt rows n<1024: [W^T|Gc|cstc|pad]; rows 1024..1088: [Gb-col profiles|cstb].
// Wb rows n<1024: [W|Gb|cstb|pad];  rows 1024..1088: [Gc-col profiles|cstc].
__global__ __launch_bounds__(256) void k_prep(const float* __restrict__ W,
                                              const float* __restrict__ Gb,
                                              const float* __restrict__ Gc,
                                              const float* __restrict__ cstb,
                                              const float* __restrict__ cstc,
                                              unsigned char* __restrict__ Wt,
                                              unsigned char* __restrict__ Wb) {
  int k = blockIdx.x * 256 + threadIdx.x;
  int n = blockIdx.y;
  if (k >= LDA) return;
  unsigned char wt = 0, wb = 0;
  if (n < 1024) {
    if (k < 1024) {
      wt = f2e4m3(W[(size_t)k * 1024 + n]);
      wb = f2e4m3(W[(size_t)n * 1024 + k]);
    } else if (k < 1088) {
      int j = k - 1024;
      wt = f2e4m3(Gc[(size_t)n * 64 + j]);
      wb = f2e4m3(Gb[(size_t)n * 64 + j]);
    } else if (k == 1088) {
      wt = f2e4m3(cstc[n]);
      wb = f2e4m3(cstb[n]);
    }
  } else if (k < 1024) {
    if (n < 1088) {
      wt = f2e4m3(Gb[(size_t)k * 64 + (n - 1024)]);
      wb = f2e4m3(Gc[(size_t)k * 64 + (n - 1024)]);
    } else if (n == 1088) {
      wt = f2e4m3(cstb[k]);
      wb = f2e4m3(cstc[k]);
    }
  }
  Wt[(size_t)n * LDA + k] = wt;
  Wb[(size_t)n * LDA + k] = wb;
}

__global__ __launch_bounds__(256) void k_wcs(const float* __restrict__ W, float* __restrict__ wcs) {
  int n = blockIdx.x * 256 + threadIdx.x;
  float s = 0.f;
  for (int i = 0; i < 1024; i++) s += W[(size_t)i * 1024 + n];
  wcs[n] = s;
}

// aux[k<64] = sum_j Gb[j][k]; aux[64] = sum_j cstb[j]
__global__ __launch_bounds__(128) void k_aux(const float* __restrict__ Gb,
                                             const float* __restrict__ cstb,
                                             float* __restrict__ aux) {
  int t = threadIdx.x;
  if (t < 64) {
    float s = 0.f;
    for (int j = 0; j < 1024; j++) s += Gb[(size_t)j * 64 + t];
    aux[t] = s;
  } else if (t == 64) {
    float s = 0.f;
    for (int j = 0; j < 1024; j++) s += cstb[j];
    aux[64] = s;
  }
}

// out[128 x 128] = X @ G^T + cst, stored bf16 (cmod only)
__global__ __launch_bounds__(256) void k_bmod(const float* __restrict__ X,
                                              const float* __restrict__ G,
                                              const float* __restrict__ cst,
                                              unsigned short* __restrict__ out) {
  __shared__ __align__(16) float Xs[128 * 64];
  __shared__ __align__(16) float Gs[128 * 64];
  const int t = threadIdx.x;
  const int r0 = blockIdx.x * 128, c0 = blockIdx.y * 128;
#pragma unroll
  for (int c = 0; c < 8; ++c) {
    int i4 = c * 256 + t;
    ((float4*)Xs)[i4] = ((const float4*)(X + (size_t)r0 * 64))[i4];
    ((float4*)Gs)[i4] = ((const float4*)(G + (size_t)c0 * 64))[i4];
  }
  __syncthreads();
  const int tr = (t >> 4) * 8, tc = (t & 15) * 8;
  float acc[8][8] = {};
  for (int k = 0; k < 64; k += 4) {
    float4 xa[8], gb[8];
#pragma unroll
    for (int i = 0; i < 8; i++) xa[i] = *(const float4*)(Xs + (tr + i) * 64 + k);
#pragma unroll
    for (int j = 0; j < 8; j++) gb[j] = *(const float4*)(Gs + (tc + j) * 64 + k);
#pragma unroll
    for (int i = 0; i < 8; i++)
#pragma unroll
      for (int j = 0; j < 8; j++)
        acc[i][j] += xa[i].x * gb[j].x + xa[i].y * gb[j].y + xa[i].z * gb[j].z + xa[i].w * gb[j].w;
  }
#pragma unroll
  for (int i = 0; i < 8; i++)
#pragma unroll
    for (int j = 0; j < 8; j++)
      out[(size_t)(r0 + tr + i) * 1024 + (c0 + tc + j)] = f2bf(acc[i][j] + cst[c0 + tc + j]);
}

__global__ __launch_bounds__(256) void k_sinit(const float* __restrict__ vdata,
                                               const float* __restrict__ X,
                                               unsigned char* __restrict__ S,
                                               unsigned char* __restrict__ H,
                                               unsigned char* __restrict__ V) {
  int k = blockIdx.x * 256 + threadIdx.x;
  int r = blockIdx.y;
  if (k >= LDA) return;
  const size_t o = (size_t)r * LDA + k;
  if (k < 1024) {
    float vd = vdata[(size_t)r * 1024 + k];
    V[o] = (vd != 0.f) ? ONE8 : (unsigned char)0;
    const bool u0 = rng_u01(USALT, (unsigned)r) < 0.5f;  // == resolver u_{-1}
    float sv = u0 ? vd : 1.f - vd;
    S[o] = (sv != 0.f) ? ONE8 : (unsigned char)0;
  } else {
    unsigned char xv;
    if (k < 1088) xv = f2e4m3(X[(size_t)r * 64 + (k - 1024)]);
    else if (k == 1088) xv = ONE8;  // 1.0
    else xv = 0;
    S[o] = xv; H[o] = xv;
  }
}

// Resolve the u Markov chain from per-step scalars. chains layout:
// [t][0]=hz [t][1]=hw [t][2]=sbm [t][3]=hcm, each NB floats.
__global__ __launch_bounds__(256) void k_uchain(const float* __restrict__ Xf,
                                                const float* __restrict__ aux,
                                                const float* __restrict__ chains,
                                                unsigned char* __restrict__ ufin) {
  __shared__ float ax[65];
  int t0 = threadIdx.x;
  if (t0 < 65) ax[t0] = aux[t0];
  __syncthreads();
  int r = blockIdx.x * 256 + t0;
  float sb = ax[64];
  const float* xr = Xf + (size_t)r * 64;
#pragma unroll
  for (int k = 0; k < 64; k++) sb += xr[k] * ax[k];
  bool u = rng_u01(USALT, (unsigned)r) < 0.5f;  // u_{-1}, matches k_sinit
  for (int t = 0; t < KSTEPS; t++) {
    const float hz = chains[(size_t)(4 * t + 0) * NB + r];
    const float hw = chains[(size_t)(4 * t + 1) * NB + r];
    const float sbm = chains[(size_t)(4 * t + 2) * NB + r];
    const float hcm = chains[(size_t)(4 * t + 3) * NB + r];
    const float hD = hz - hcm;                   // sum_h h*(sW)[h]
    const float va = u ? hD : (hw - hD);         // sum v*a
    const float vbm = u ? sbm : (sb - sbm);      // sum v*b_mod
    const float dE = -(hw + sb) + 2.f * (va + vbm);
    u = rng_u01(USALT + 1u + (unsigned)t, (unsigned)r) < sigm(dE);
  }
  ufin[r] = u ? (unsigned char)1 : (unsigned char)0;
}

__global__ __launch_bounds__(256) void k_final(
    const float* __restrict__ Xf, const float* __restrict__ aux,
    const unsigned char* __restrict__ ufin,
    const float* __restrict__ spn_d, const float* __restrict__ spf_d,
    const float* __restrict__ spn_m, const float* __restrict__ spf_m,
    const float* __restrict__ vb_d, const float* __restrict__ vb_m,
    float* __restrict__ fdiff) {
  __shared__ float ax[65];
  int t = threadIdx.x;
  if (t < 65) ax[t] = aux[t];
  __syncthreads();
  int r = blockIdx.x * 256 + t;
  float sb = ax[64];
  const float* xr = Xf + (size_t)r * 64;
#pragma unroll
  for (int k = 0; k < 64; k++) sb += xr[k] * ax[k];
  const bool uu = ufin[r] != 0;
  const float d1 = vb_d[r], d2 = vb_m[r];
  float F_d = -lse2(d1 + spn_d[r], (sb - d1) + spf_d[r]);
  float vbn = uu ? d2 : (sb - d2);
  float F_m = -lse2(vbn + spn_m[r], (sb - vbn) + spf_m[r]);
  fdiff[r] = F_d - F_m;
}

__global__ __launch_bounds__(256) void k_reduce(const float* __restrict__ fdiff,
                                                float* __restrict__ out) {
  __shared__ float red[4];
  int t = threadIdx.x;
  float s = 0.f;
  for (int i = t; i < NB; i += 256) s += fdiff[i];
  for (int m = 32; m >= 1; m >>= 1) s += __shfl_xor(s, m, 64);
  if ((t & 63) == 0) red[t >> 6] = s;
  __syncthreads();
  if (t == 0) out[0] = (red[0] + red[1] + red[2] + red[3]) * (1.0f / (float)NB);
}

// ---------------------------------------------------------------------------
extern "C" void kernel_launch(void* const* d_in, const int* in_sizes, int n_in, void* d_out,
                              int out_size, void* d_ws, size_t ws_size, hipStream_t stream) {
  const float* vdata = (const float*)d_in[0];
  const float* cond = (const float*)d_in[1];
  const float* W = (const float*)d_in[2];
  const float* bb = (const float*)d_in[3];
  const float* cc = (const float*)d_in[4];
  const float* fc1w = (const float*)d_in[5];
  const float* fc1b = (const float*)d_in[6];
  const float* fc2w = (const float*)d_in[7];
  const float* fc2b = (const float*)d_in[8];
  float* out = (float*)d_out;

  char* wp = (char*)d_ws;
  auto alloc = [&](size_t bytes) {
    char* p = wp;
    wp += (bytes + 255) & ~(size_t)255;
    return p;
  };
  unsigned char* Wt = (unsigned char*)alloc((size_t)1152 * LDA);
  unsigned char* Wb = (unsigned char*)alloc((size_t)1152 * LDA);
  float* wcs = (float*)alloc(1024 * 4);
  float* X = (float*)alloc((size_t)NB * 64 * 4);
  float* Gb = (float*)alloc((size_t)1024 * 64 * 4);
  float* Gc = (float*)alloc((size_t)1024 * 64 * 4);
  float* cstb = (float*)alloc(1024 * 4);
  float* cstc = (float*)alloc(1024 * 4);
  float* aux = (float*)alloc(65 * 4);
  unsigned short* cmod = (unsigned short*)alloc((size_t)NB * 1024 * 2);
  unsigned char* S = (unsigned char*)alloc((size_t)NB * LDA);
  unsigned char* H = (unsigned char*)alloc((size_t)NB * LDA);
  unsigned char* V = (unsigned char*)alloc((size_t)NB * LDA);
  // chains: [t][{hz,hw,sbm,hcm}][NB]; then sp arrays + vb arrays (zeroed together)
  float* chains = (float*)alloc((size_t)(4 * KSTEPS + 6) * NB * 4);
  float* spn_d = chains + (size_t)4 * KSTEPS * NB;
  float* spf_d = spn_d + NB;
  float* spn_m = spf_d + NB;
  float* spf_m = spn_m + NB;
  float* vb_d = spf_m + NB;
  float* vb_m = vb_d + NB;
  unsigned char* ufin = (unsigned char*)alloc(NB);
  float* fdiff = (float*)alloc(NB * 4);
  auto CH = [&](int t, int which) { return chains + (size_t)(4 * t + which) * NB; };

  hipMemsetAsync(chains, 0, (size_t)(4 * KSTEPS + 6) * NB * 4, stream);

  k_x<<<NB * 64 / 256, 256, 0, stream>>>(cond, fc1w, fc1b, X);
  k_g<<<1024 * 64 / 256, 256, 0, stream>>>(fc2w, fc2b, bb, cc, Gb, Gc, cstb, cstc);
  k_prep<<<dim3(5, 1152), 256, 0, stream>>>(W, Gb, Gc, cstb, cstc, Wt, Wb);
  k_wcs<<<4, 256, 0, stream>>>(W, wcs);
  k_aux<<<1, 128, 0, stream>>>(Gb, cstb, aux);
  k_bmod<<<dim3(NB / 128, 8), 256, 0, stream>>>(X, Gc, cstc, cmod);
  k_sinit<<<dim3(5, NB), 256, 0, stream>>>(vdata, X, S, H, V);

  for (int step = 0; step < KSTEPS; ++step) {
    // z1 = sW + c_mod; h -> H; hz,hw reduced; mini-tile: sbm = S.bmod
    gemm_bt<0><<<1024, 256, 0, stream>>>(S, Wt, H, nullptr, wcs, X, nullptr,
                                         CH(step, 0), CH(step, 1), CH(step, 2),
                                         2000u + (unsigned)step, LDA);
    // z2 = hW^T + b_mod; s -> S (pure sampler); mini-tile: hcm = sum h*cmod
    gemm_bt<1><<<1024, 256, 0, stream>>>(H, Wb, S, nullptr, nullptr, X, nullptr,
                                         nullptr, nullptr, CH(step, 3),
                                         3000u + (unsigned)step, LDA);
  }

  // Resolve u chain, then free-energy passes (mini-tile: vb = V/S . bmod).
  k_uchain<<<NB / 256, 256, 0, stream>>>(X, aux, chains, ufin);
  gemm_bt<2><<<1024, 256, 0, stream>>>(V, Wt, nullptr, cmod, wcs, X, nullptr,
                                       spn_d, spf_d, vb_d, 0u, 1024);
  gemm_bt<2><<<1024, 256, 0, stream>>>(S, Wt, nullptr, cmod, wcs, X, ufin,
                                       spn_m, spf_m, vb_m, 0u, 1024);
  k_final<<<NB / 256, 256, 0, stream>>>(X, aux, ufin, spn_d, spf_d, spn_m, spf_m,
                                        vb_d, vb_m, fdiff);
  k_reduce<<<1, 256, 0, stream>>>(fdiff, out);
}

// Round 13
// 1629.699 us; speedup vs baseline: 1.6036x; 1.6036x over previous
//
#include <hip/hip_runtime.h>
#include <hip/hip_bf16.h>
#include <stdint.h>

// SymmetricHyperRBM on MI355X. K=10 Gibbs chain + free-energy gap.
// fp8 e4m3; FiLM biases folded into GEMM K-dim; XCD swizzle; inline-u chain
// (R9 structure — best passing). R13: 64x128 tiles, BK=64, grid 2048
// -> 8 blocks/CU = 32 waves/CU (R9's 128x128/grid-1024 capped at 16).
// LDS 12 KB/block; double-XOR chunk swizzle pc = q ^ (row&3) ^ ((row>>2)&3)
// keeps fp8 b64 fragment reads at <=2 lanes/bank (2-way = free, m136).

#define NB 16384
#define KSTEPS 10
#define LDA 1152           // bytes/row: 1024 state + 64 X + 1 const + 63 pad
#define SLS 136            // epilogue slab row stride in bytes (128 + 8 pad)
#define USALT 4000u
#define ONE8 ((unsigned char)0x38)  // fp8 e4m3 1.0

typedef __attribute__((ext_vector_type(4))) float f32x4;
typedef __attribute__((ext_vector_type(4))) unsigned int u32x4;

__device__ __forceinline__ unsigned hash32(unsigned idx, unsigned salt) {
  unsigned x = idx + salt * 0x9E3779B9u;
  x = (x ^ (x >> 16)) * 0x7feb352du;
  x = (x ^ (x >> 15)) * 0x846ca68bu;
  return x ^ (x >> 16);
}
__device__ __forceinline__ float rng_u01(unsigned salt, unsigned idx) {
  return (float)(hash32(idx, salt) >> 8) * (1.0f / 16777216.0f);
}
__device__ __forceinline__ float sigm(float z) { return 1.0f / (1.0f + __expf(-z)); }
__device__ __forceinline__ float softplus_(float z) {
  return z > 0.f ? z + log1pf(__expf(-z)) : log1pf(__expf(z));
}
__device__ __forceinline__ float lse2(float a, float b) {
  float m = fmaxf(a, b);
  return m + log1pf(__expf(fminf(a, b) - m));
}
__device__ __forceinline__ float bf2f(unsigned short s) {
  unsigned u = ((unsigned)s) << 16;
  return *reinterpret_cast<float*>(&u);
}
__device__ __forceinline__ unsigned short f2bf(float f) {
  __hip_bfloat16 h = __float2bfloat16(f);
  return *reinterpret_cast<unsigned short*>(&h);
}
// float -> fp8 e4m3fn (OCP), RNE, saturating. Setup-path only.
__device__ unsigned char f2e4m3(float f) {
  unsigned u = __float_as_uint(f);
  unsigned char s = (unsigned char)((u >> 24) & 0x80);
  float af = fabsf(f);
  if (af >= 448.f) return s | 0x7E;
  float sub = rintf(af * 512.f);
  if (sub < 1.f) return s;                 // underflow -> 0
  if (af < 0.015625f) {                    // subnormal, step 2^-9
    int m = (int)sub;
    if (m > 7) return s | 0x08;
    return s | (unsigned char)m;
  }
  int ex; frexpf(af, &ex);
  int E = ex - 1;                          // af in [2^E, 2^(E+1))
  float q = rintf(ldexpf(af, 3 - E));      // in [8,16]
  int qi = (int)q;
  if (qi >= 16) { qi = 8; E += 1; if (E > 8) return s | 0x7E; }
  return s | (unsigned char)(((E + 7) << 3) | (qi - 8));
}
__device__ __forceinline__ void gl2lds16(const void* g, void* l) {
  __builtin_amdgcn_global_load_lds(
      (const __attribute__((address_space(1))) unsigned int*)g,
      (__attribute__((address_space(3))) unsigned int*)l, 16, 0, 0);
}

// ---------------------------------------------------------------------------
// C = A[16384 x Kdim] * Bt[. x Kdim]^T, fp8 MFMA 16x16x32, 64x128 tile, BK=64.
// Grid 2048 (chain) / 2304 (EPI2 incl. bias n-tile 8):
//   xcd=L&7, li=L>>3; m0 = xcd*2048 + (li&31)*64; n-tile = li>>5.
// EPI 0: h = bern(sigm(z1)) -> sh (pure sampler).
// EPI 1: u_t inline from (pv0,pv1,usalt); p0+=sum z, p1+=sum v*z
//        (v = u_t ? s_old : 1-s_old, scattered L2 reads); s_new -> sh.
// EPI 2: n<8: softplus rows (cmod NT; u inline or pv0=null=data) -> p0,p1;
//        n==8: bias-dots (acc . X -> p2).
// ---------------------------------------------------------------------------
template <int EPI>
__global__ __launch_bounds__(256, 8) void gemm_bt(
    const unsigned char* __restrict__ A, const unsigned char* __restrict__ Bt,
    unsigned char* sh, const unsigned short* __restrict__ mod,
    const float* __restrict__ wcs, const float* __restrict__ Xf,
    const float* __restrict__ pv0, const float* __restrict__ pv1, unsigned usalt,
    float* __restrict__ p0, float* __restrict__ p1, float* __restrict__ p2,
    unsigned salt, int Kdim) {
  // staging: As [0,4K) Bs [4K,12K); epilogue slab 64 x 136 B aliases the front
  __shared__ __align__(16) char smem[12288];
  unsigned char* newsl = (unsigned char*)smem;

  const int t = threadIdx.x;
  const int L = blockIdx.x;
  const int xcd = L & 7, li = L >> 3;
  const int m0 = xcd * 2048 + (li & 31) * 64;
  const int n0 = (li >> 5) * 128;
  const int lane = t & 63, wave = t >> 6;
  const int wm = (wave >> 1) * 32, wn = (wave & 1) * 64;
  const int lr = lane & 15, quad = lane >> 4;
  // staging: lane -> row = lane>>2, phys chunk lane&3; gathers LOGICAL chunk
  // q = (lane&3) ^ (row&3) ^ ((lane>>4)&3)   [double-XOR swizzle]
  const int row8 = lane >> 2;
  const int qch = (((lane & 3) ^ (row8 & 3) ^ ((lane >> 4) & 3)) << 4);
  // fragment read offsets: phys chunk = (s*2+qh) ^ (lr&3) ^ ((lr>>2)&3)
  const int ql8 = (quad & 1) * 8, qh = quad >> 1;
  const int rx = (lr & 3) ^ ((lr >> 2) & 3);
  int koff[2];
#pragma unroll
  for (int s = 0; s < 2; ++s) koff[s] = (((s * 2 + qh) ^ rx) << 4) + ql8;

  // hoisted staging pointers (advance 64 B per K-iter)
  const unsigned char* gA = A + (size_t)(m0 + wave * 16 + row8) * LDA + qch;
  const unsigned char* gB0 = Bt + (size_t)(n0 + wave * 32 + row8) * LDA + qch;
  const unsigned char* gB1 = gB0 + (size_t)16 * LDA;

  f32x4 acc[2][4] = {};

  for (int k0 = 0; k0 < Kdim; k0 += 64) {
    gl2lds16(gA, smem + wave * 1024);
    gA += 64;
    gl2lds16(gB0, smem + 4096 + wave * 2048);
    gB0 += 64;
    gl2lds16(gB1, smem + 4096 + wave * 2048 + 1024);
    gB1 += 64;
    __syncthreads();
#pragma unroll
    for (int s = 0; s < 2; ++s) {  // two K=32 slices of the 64-B row
      long af[2], bfr[4];
#pragma unroll
      for (int i = 0; i < 2; i++)
        af[i] = *(const long*)(smem + (wm + i * 16 + lr) * 64 + koff[s]);
#pragma unroll
      for (int j = 0; j < 4; j++)
        bfr[j] = *(const long*)(smem + 4096 + (wn + j * 16 + lr) * 64 + koff[s]);
#pragma unroll
      for (int i = 0; i < 2; i++)
#pragma unroll
        for (int j = 0; j < 4; j++)
          acc[i][j] = __builtin_amdgcn_mfma_f32_16x16x32_fp8_fp8(af[i], bfr[j], acc[i][j], 0, 0, 0);
    }
    __syncthreads();
  }

  // C/D layout (m89, dtype-independent): col = lane&15, row = quad*4 + reg
  if constexpr (EPI == 2) {
    if (n0 >= 1024) {  // bias-dot tile: cols 1024..1088 = [Gb-dots | cstb]
#pragma unroll
      for (int i = 0; i < 2; i++)
#pragma unroll
        for (int rg = 0; rg < 4; rg++) {
          const int r = m0 + wm + i * 16 + quad * 4 + rg;
          float pb = 0.f;
          if (wn == 0) {  // cg = j*16+lr in 0..63: G-dots with X[r]
#pragma unroll
            for (int j = 0; j < 4; j++)
              pb += acc[i][j][rg] * Xf[(size_t)r * 64 + j * 16 + lr];
          } else {        // col 1088 (j==0,lr==0): cst-dot
            if (lr == 0) pb = acc[i][0][rg];
          }
#pragma unroll
          for (int msk = 1; msk < 16; msk <<= 1) pb += __shfl_xor(pb, msk, 64);
          if (lr == 0) atomicAdd(&p2[r], pb);
        }
      return;
    }
#pragma unroll
    for (int i = 0; i < 2; i++)
#pragma unroll
      for (int rg = 0; rg < 4; rg++) {
        const int r = m0 + wm + i * 16 + quad * 4 + rg;
        bool uu = true;
        if (pv0 != nullptr) {
          const float dE = -pv0[r] + 2.f * pv1[r];
          uu = rng_u01(usalt, (unsigned)r) < sigm(dE);
        }
        float sn = 0.f, sf = 0.f;
#pragma unroll
        for (int j = 0; j < 4; j++) {
          const int n = n0 + wn + j * 16 + lr;
          const float vw = acc[i][j][rg];
          const float cm = bf2f(__builtin_nontemporal_load(mod + (size_t)r * 1024 + n));
          const float s1 = softplus_(vw + cm);
          const float s2 = softplus_(wcs[n] - vw + cm);
          sn += uu ? s1 : s2;
          sf += uu ? s2 : s1;
        }
#pragma unroll
        for (int msk = 1; msk < 16; msk <<= 1) {
          sn += __shfl_xor(sn, msk, 64);
          sf += __shfl_xor(sf, msk, 64);
        }
        if (lr == 0) { atomicAdd(&p0[r], sn); atomicAdd(&p1[r], sf); }
      }
    return;
  }

  if constexpr (EPI == 1) {  // z-sums with v from OLD s; u_t inline
#pragma unroll
    for (int i = 0; i < 2; i++)
#pragma unroll
      for (int rg = 0; rg < 4; rg++) {
        const int r = m0 + wm + i * 16 + quad * 4 + rg;
        const float dE = -pv0[r] + 2.f * pv1[r];
        const bool uu = rng_u01(usalt, (unsigned)r) < sigm(dE);
        float q0 = 0.f, q1 = 0.f;
#pragma unroll
        for (int j = 0; j < 4; ++j) {
          const float z = acc[i][j][rg];
          const float so = (sh[(size_t)r * LDA + n0 + wn + j * 16 + lr] != 0) ? 1.f : 0.f;
          const float v = uu ? so : 1.f - so;
          q0 += z; q1 += v * z;
        }
#pragma unroll
        for (int msk = 1; msk < 16; msk <<= 1) {
          q0 += __shfl_xor(q0, msk, 64);
          q1 += __shfl_xor(q1, msk, 64);
        }
        if (lr == 0) { atomicAdd(&p0[r], q0); atomicAdd(&p1[r], q1); }
      }
  }

  // EPI 0/1: sample into 64-row slab, 1 barrier, coalesced store
#pragma unroll
  for (int i = 0; i < 2; ++i)
#pragma unroll
    for (int rg = 0; rg < 4; ++rg) {
      const int rowl = wm + i * 16 + quad * 4 + rg;  // 0..63 in tile
      const int r = m0 + rowl;
#pragma unroll
      for (int jp = 0; jp < 2; ++jp) {
        const unsigned x = hash32((unsigned)(r << 10) + (unsigned)(n0 + wn + jp * 16 + lr), salt);
        const float f0 = (float)(x & 0xFFFFu), f1 = (float)(x >> 16);
        const float z0 = acc[i][jp][rg], z1v = acc[i][jp + 2][rg];
        newsl[rowl * SLS + wn + jp * 16 + lr] =
            (f0 * __expf(-z0) < 65536.f - f0) ? ONE8 : (unsigned char)0;
        newsl[rowl * SLS + wn + (jp + 2) * 16 + lr] =
            (f1 * __expf(-z1v) < 65536.f - f1) ? ONE8 : (unsigned char)0;
      }
    }
  __syncthreads();
#pragma unroll
  for (int p = 0; p < 2; ++p) {  // 64 rows x 128 B, fully coalesced
    const int c = p * 256 + t, rowl = c >> 3, chk = c & 7;
    const u32x4 vv = *(const u32x4*)(newsl + rowl * SLS + chk * 16);
    *(u32x4*)(sh + (size_t)(m0 + rowl) * LDA + n0 + chk * 16) = vv;
  }
}

// ------------------------- setup / small kernels ---------------------------
__global__ __launch_bounds__(256) void k_x(const float* __restrict__ cond,
                                           const float* __restrict__ fc1w,
                                           const float* __restrict__ fc1b, float* __restrict__ X) {
  int idx = blockIdx.x * 256 + threadIdx.x;
  int r = idx >> 6, k = idx & 63;
  X[idx] = tanhf(cond[r] * fc1w[k] + fc1b[k]);
}

__global__ __launch_bounds__(256) void k_g(const float* __restrict__ fc2w,
                                           const float* __restrict__ fc2b,
                                           const float* __restrict__ b, const float* __restrict__ c,
                                           float* __restrict__ Gb, float* __restrict__ Gc,
                                           float* __restrict__ cstb, float* __restrict__ cstc) {
  int idx = blockIdx.x * 256 + threadIdx.x;
  int j = idx >> 6, k = idx & 63;
  Gb[idx] = fc2w[(size_t)j * 64 + k] * b[j] + fc2w[(size_t)(1024 + j) * 64 + k];
  Gc[idx] = fc2w[(size_t)(2048 + j) * 64 + k] * c[j] + fc2w[(size_t)(3072 + j) * 64 + k];
  if (k == 0) {
    cstb[j] = b[j] + fc2b[j] * b[j] + fc2b[1024 + j];
    cstc[j] = c[j] + fc2b[2048 + j] * c[j] + fc2b[3072 + j];
  }
}

// Wt rows n<1024: [W^T|Gc|cstc|pad]; rows 1024..1088: [Gb-col profiles|cstb].
// Wb rows n<1024: [W|Gb|cstb|pad]; rows beyond unused for Wb.
__global__ __launch_bounds__(256) void k_prep(const float* __restrict__ W,
                                              const float* __restrict__ Gb,
                                              const float* __restrict__ Gc,
                                              const float* __restrict__ cstb,
                                              const float* __restrict__ cstc,
                                              unsigned char* __restrict__ Wt,
                                              unsigned char* __restrict__ Wb) {
  int k = blockIdx.x * 256 + threadIdx.x;
  int n = blockIdx.y;
  if (k >= LDA) return;
  unsigned char wt = 0, wb = 0;
  if (n < 1024) {
    if (k < 1024) {
      wt = f2e4m3(W[(size_t)k * 1024 + n]);
      wb = f2e4m3(W[(size_t)n * 1024 + k]);
    } else if (k < 1088) {
      int j = k - 1024;
      wt = f2e4m3(Gc[(size_t)n * 64 + j]);
      wb = f2e4m3(Gb[(size_t)n * 64 + j]);
    } else if (k == 1088) {
      wt = f2e4m3(cstc[n]);
      wb = f2e4m3(cstb[n]);
    }
  } else if (k < 1024) {
    if (n < 1088) wt = f2e4m3(Gb[(size_t)k * 64 + (n - 1024)]);
    else if (n == 1088) wt = f2e4m3(cstb[k]);
  }
  Wt[(size_t)n * LDA + k] = wt;
  Wb[(size_t)n * LDA + k] = wb;
}

__global__ __launch_bounds__(256) void k_wcs(const float* __restrict__ W, float* __restrict__ wcs) {
  int n = blockIdx.x * 256 + threadIdx.x;
  float s = 0.f;
  for (int i = 0; i < 1024; i++) s += W[(size_t)i * 1024 + n];
  wcs[n] = s;
}

// aux[k<64] = sum_j Gb[j][k]; aux[64] = sum_j cstb[j]
__global__ __launch_bounds__(128) void k_aux(const float* __restrict__ Gb,
                                             const float* __restrict__ cstb,
                                             float* __restrict__ aux) {
  int t = threadIdx.x;
  if (t < 64) {
    float s = 0.f;
    for (int j = 0; j < 1024; j++) s += Gb[(size_t)j * 64 + t];
    aux[t] = s;
  } else if (t == 64) {
    float s = 0.f;
    for (int j = 0; j < 1024; j++) s += cstb[j];
    aux[64] = s;
  }
}

// out[128 x 128] = X @ G^T + cst, stored bf16 (cmod only)
__global__ __launch_bounds__(256) void k_bmod(const float* __restrict__ X,
                                              const float* __restrict__ G,
                                              const float* __restrict__ cst,
                                              unsigned short* __restrict__ out) {
  __shared__ __align__(16) float Xs[128 * 64];
  __shared__ __align__(16) float Gs[128 * 64];
  const int t = threadIdx.x;
  const int r0 = blockIdx.x * 128, c0 = blockIdx.y * 128;
#pragma unroll
  for (int c = 0; c < 8; ++c) {
    int i4 = c * 256 + t;
    ((float4*)Xs)[i4] = ((const float4*)(X + (size_t)r0 * 64))[i4];
    ((float4*)Gs)[i4] = ((const float4*)(G + (size_t)c0 * 64))[i4];
  }
  __syncthreads();
  const int tr = (t >> 4) * 8, tc = (t & 15) * 8;
  float acc[8][8] = {};
  for (int k = 0; k < 64; k += 4) {
    float4 xa[8], gb[8];
#pragma unroll
    for (int i = 0; i < 8; i++) xa[i] = *(const float4*)(Xs + (tr + i) * 64 + k);
#pragma unroll
    for (int j = 0; j < 8; j++) gb[j] = *(const float4*)(Gs + (tc + j) * 64 + k);
#pragma unroll
    for (int i = 0; i < 8; i++)
#pragma unroll
      for (int j = 0; j < 8; j++)
        acc[i][j] += xa[i].x * gb[j].x + xa[i].y * gb[j].y + xa[i].z * gb[j].z + xa[i].w * gb[j].w;
  }
#pragma unroll
  for (int i = 0; i < 8; i++)
#pragma unroll
    for (int j = 0; j < 8; j++)
      out[(size_t)(r0 + tr + i) * 1024 + (c0 + tc + j)] = f2bf(acc[i][j] + cst[c0 + tc + j]);
}

__global__ __launch_bounds__(256) void k_sinit(const float* __restrict__ vdata,
                                               const float* __restrict__ X,
                                               unsigned char* __restrict__ S,
                                               unsigned char* __restrict__ H,
                                               unsigned char* __restrict__ V) {
  int k = blockIdx.x * 256 + threadIdx.x;
  int r = blockIdx.y;
  if (k >= LDA) return;
  const size_t o = (size_t)r * LDA + k;
  if (k < 1024) {
    float vd = vdata[(size_t)r * 1024 + k];
    V[o] = (vd != 0.f) ? ONE8 : (unsigned char)0;
    const bool u0 = rng_u01(USALT, (unsigned)r) < 0.5f;  // == EPI1 step-0 formula
    float sv = u0 ? vd : 1.f - vd;
    S[o] = (sv != 0.f) ? ONE8 : (unsigned char)0;
  } else {
    unsigned char xv;
    if (k < 1088) xv = f2e4m3(X[(size_t)r * 64 + (k - 1024)]);
    else if (k == 1088) xv = ONE8;  // 1.0
    else xv = 0;
    S[o] = xv; H[o] = xv;
  }
}

// per-row scalar finale: sb from rank-64 closed form, d1/d2 from bias-dots
__global__ __launch_bounds__(256) void k_final(
    const float* __restrict__ Xf, const float* __restrict__ aux,
    const float* __restrict__ pv0, const float* __restrict__ pv1, unsigned usalt,
    const float* __restrict__ spn_d, const float* __restrict__ spf_d,
    const float* __restrict__ spn_m, const float* __restrict__ spf_m,
    const float* __restrict__ vb_d, const float* __restrict__ vb_m,
    float* __restrict__ fdiff) {
  __shared__ float ax[65];
  int t = threadIdx.x;
  if (t < 65) ax[t] = aux[t];
  __syncthreads();
  int r = blockIdx.x * 256 + t;
  float sb = ax[64];
  const float* xr = Xf + (size_t)r * 64;
#pragma unroll
  for (int k = 0; k < 64; k++) sb += xr[k] * ax[k];
  const float dE = -pv0[r] + 2.f * pv1[r];
  const bool uu = rng_u01(usalt, (unsigned)r) < sigm(dE);
  const float d1 = vb_d[r], d2 = vb_m[r];
  float F_d = -lse2(d1 + spn_d[r], (sb - d1) + spf_d[r]);
  float vbn = uu ? d2 : (sb - d2);
  float F_m = -lse2(vbn + spn_m[r], (sb - vbn) + spf_m[r]);
  fdiff[r] = F_d - F_m;
}

__global__ __launch_bounds__(256) void k_reduce(const float* __restrict__ fdiff,
                                                float* __restrict__ out) {
  __shared__ float red[4];
  int t = threadIdx.x;
  float s = 0.f;
  for (int i = t; i < NB; i += 256) s += fdiff[i];
  for (int m = 32; m >= 1; m >>= 1) s += __shfl_xor(s, m, 64);
  if ((t & 63) == 0) red[t >> 6] = s;
  __syncthreads();
  if (t == 0) out[0] = (red[0] + red[1] + red[2] + red[3]) * (1.0f / (float)NB);
}

// ---------------------------------------------------------------------------
extern "C" void kernel_launch(void* const* d_in, const int* in_sizes, int n_in, void* d_out,
                              int out_size, void* d_ws, size_t ws_size, hipStream_t stream) {
  const float* vdata = (const float*)d_in[0];
  const float* cond = (const float*)d_in[1];
  const float* W = (const float*)d_in[2];
  const float* bb = (const float*)d_in[3];
  const float* cc = (const float*)d_in[4];
  const float* fc1w = (const float*)d_in[5];
  const float* fc1b = (const float*)d_in[6];
  const float* fc2w = (const float*)d_in[7];
  const float* fc2b = (const float*)d_in[8];
  float* out = (float*)d_out;

  char* wp = (char*)d_ws;
  auto alloc = [&](size_t bytes) {
    char* p = wp;
    wp += (bytes + 255) & ~(size_t)255;
    return p;
  };
  unsigned char* Wt = (unsigned char*)alloc((size_t)1152 * LDA);
  unsigned char* Wb = (unsigned char*)alloc((size_t)1152 * LDA);
  float* wcs = (float*)alloc(1024 * 4);
  float* X = (float*)alloc((size_t)NB * 64 * 4);
  float* Gb = (float*)alloc((size_t)1024 * 64 * 4);
  float* Gc = (float*)alloc((size_t)1024 * 64 * 4);
  float* cstb = (float*)alloc(1024 * 4);
  float* cstc = (float*)alloc(1024 * 4);
  float* aux = (float*)alloc(65 * 4);
  unsigned short* cmod = (unsigned short*)alloc((size_t)NB * 1024 * 2);
  unsigned char* S = (unsigned char*)alloc((size_t)NB * LDA);
  unsigned char* H = (unsigned char*)alloc((size_t)NB * LDA);
  unsigned char* V = (unsigned char*)alloc((size_t)NB * LDA);
  // per-step dE accumulators: pair t at pall + (t+1)*2*NB, t=-1..9; then 6 arrays
  float* pall = (float*)alloc((size_t)(KSTEPS + 1 + 3) * 2 * NB * 4);
  float* spn_d = pall + (size_t)(KSTEPS + 1) * 2 * NB;
  float* spf_d = spn_d + NB;
  float* spn_m = spf_d + NB;
  float* spf_m = spn_m + NB;
  float* vb_d = spf_m + NB;
  float* vb_m = vb_d + NB;
  float* fdiff = (float*)alloc(NB * 4);
  auto P0 = [&](int t) { return pall + (size_t)(t + 1) * 2 * NB; };
  auto P1 = [&](int t) { return pall + (size_t)(t + 1) * 2 * NB + NB; };

  hipMemsetAsync(pall, 0, (size_t)(KSTEPS + 1 + 3) * 2 * NB * 4, stream);

  k_x<<<NB * 64 / 256, 256, 0, stream>>>(cond, fc1w, fc1b, X);
  k_g<<<1024 * 64 / 256, 256, 0, stream>>>(fc2w, fc2b, bb, cc, Gb, Gc, cstb, cstc);
  k_prep<<<dim3(5, 1152), 256, 0, stream>>>(W, Gb, Gc, cstb, cstc, Wt, Wb);
  k_wcs<<<4, 256, 0, stream>>>(W, wcs);
  k_aux<<<1, 128, 0, stream>>>(Gb, cstb, aux);
  k_bmod<<<dim3(NB / 128, 8), 256, 0, stream>>>(X, Gc, cstc, cmod);
  k_sinit<<<dim3(5, NB), 256, 0, stream>>>(vdata, X, S, H, V);

  for (int step = 0; step < KSTEPS; ++step) {
    // z1 = sW + c_mod (ext-K); h ~ Bern(sigm(z1)) -> H
    gemm_bt<0><<<2048, 256, 0, stream>>>(S, Wt, H, nullptr, nullptr, nullptr,
                                         nullptr, nullptr, 0u, nullptr, nullptr, nullptr,
                                         2000u + (unsigned)step, LDA);
    // z2 = hW^T + b_mod (ext-K); u_t inline; dE partials -> step t; s_new -> S
    gemm_bt<1><<<2048, 256, 0, stream>>>(H, Wb, S, nullptr, nullptr, nullptr,
                                         P0(step - 1), P1(step - 1), USALT + (unsigned)step,
                                         P0(step), P1(step), nullptr,
                                         3000u + (unsigned)step, LDA);
  }

  // Free-energy: softplus rows (n-tiles 0..7) + bias-dots (n-tile 8). K=1024.
  gemm_bt<2><<<2304, 256, 0, stream>>>(V, Wt, nullptr, cmod, wcs, X, nullptr, nullptr, 0u,
                                       spn_d, spf_d, vb_d, 0u, 1024);
  gemm_bt<2><<<2304, 256, 0, stream>>>(S, Wt, nullptr, cmod, wcs, X,
                                       P0(KSTEPS - 1), P1(KSTEPS - 1), USALT + KSTEPS,
                                       spn_m, spf_m, vb_m, 0u, 1024);
  k_final<<<NB / 256, 256, 0, stream>>>(X, aux, P0(KSTEPS - 1), P1(KSTEPS - 1), USALT + KSTEPS,
                                        spn_d, spf_d, spn_m, spf_m, vb_d, vb_m, fdiff);
  k_reduce<<<1, 256, 0, stream>>>(fdiff, out);
}